// Round 8
// baseline (825.780 us; speedup 1.0000x reference)
//
#include <hip/hip_runtime.h>
#include <cstdint>
#include <cstddef>

typedef unsigned short u16;
typedef unsigned int u32;
typedef __attribute__((ext_vector_type(8))) short bf16x8;    // 8 bf16 in 4 VGPRs
typedef __attribute__((ext_vector_type(4))) float f32x4;
typedef __attribute__((ext_vector_type(16))) float f32x16;
typedef __attribute__((ext_vector_type(2))) unsigned int u32x2;

#define MFMA(a, b, c)   __builtin_amdgcn_mfma_f32_16x16x32_bf16((a), (b), (c), 0, 0, 0)
#define MFMA32(a, b, c) __builtin_amdgcn_mfma_f32_32x32x16_bf16((a), (b), (c), 0, 0, 0)

// async global->LDS, 16B per lane; LDS dest is wave-uniform base + lane*16
typedef const __attribute__((address_space(1))) void gv1_t;
typedef __attribute__((address_space(3))) void lv3_t;
#define GLOAD_LDS16(g, l) __builtin_amdgcn_global_load_lds((gv1_t*)(g), (lv3_t*)(l), 16, 0, 0)

#define BATCH 4
#define SEQ 2048
#define DMODEL 1024
#define NHEAD 16
#define MROWS (BATCH * SEQ)   // 8192
#define QKVN (3 * DMODEL)     // 3072

#define LOG2E 1.44269504088896340736f

// NOTE (round 7): inline-asm v_cvt_pk_bf16_f32 REGRESSED (+38 us total) — opaque
// to the scheduler in hot epilogues (m240 lesson confirmed). Keep integer RNE.
__device__ __forceinline__ u16 f2bf(float f) {
  u32 x = __builtin_bit_cast(u32, f);
  x += 0x7fffu + ((x >> 16) & 1u);   // RNE (values finite/normal here)
  return (u16)(x >> 16);
}

// RNE pack of two f32 -> packed bf16x2 (u32); lo = a, hi = b
__device__ __forceinline__ u32 pkbf(float a, float b) {
  return (u32)f2bf(a) | ((u32)f2bf(b) << 16);
}

// permlane32_swap: ret.x = [A(0:31), B(0:31)], ret.y = [A(32:63), B(32:63)]
__device__ __forceinline__ u32x2 plswap(u32 a, u32 b) {
  return __builtin_amdgcn_permlane32_swap(a, b, false, false);
}

extern "C" __device__ float __ocml_exp2_f32(float);
__device__ __forceinline__ float exp2fast(float x) {
#if __has_builtin(__builtin_amdgcn_exp2f)
  return __builtin_amdgcn_exp2f(x);
#else
  return __ocml_exp2_f32(x);
#endif
}

// ---------------- fp32 -> bf16 convert of hidden_states ----------------
__global__ __launch_bounds__(256) void convert_h(const float* __restrict__ H,
                                                 u16* __restrict__ Hb) {
  size_t i = (size_t)blockIdx.x * 1024 + threadIdx.x * 4;
  float4 v = *(const float4*)&H[i];
  uint2 o;
  o.x = pkbf(v.x, v.y);
  o.y = pkbf(v.z, v.w);
  *(uint2*)&Hb[i] = o;
}

// ------------- transpose + convert Wq|Wk|Wv|Wo -> Wt[4096][1024] -------------
// Wq is pre-scaled by log2(e) so attention scores land in the exp2 domain.
__global__ void transpose_w(const float* __restrict__ Wq, const float* __restrict__ Wk,
                            const float* __restrict__ Wv, const float* __restrict__ Wo,
                            u16* __restrict__ Wt) {
  __shared__ u16 Ts[32][33];
  const float* W = (blockIdx.z == 0) ? Wq : (blockIdx.z == 1) ? Wk
                   : (blockIdx.z == 2) ? Wv : Wo;
  const float s = (blockIdx.z == 0) ? LOG2E : 1.0f;
  int x = threadIdx.x, y0 = threadIdx.y;
  int r0 = blockIdx.y * 32, c0 = blockIdx.x * 32;
  for (int yy = y0; yy < 32; yy += 8)
    Ts[yy][x] = f2bf(W[(size_t)(r0 + yy) * 1024 + c0 + x] * s);
  __syncthreads();
  for (int yy = y0; yy < 32; yy += 8)
    Wt[(size_t)(blockIdx.z * 1024 + c0 + yy) * 1024 + r0 + x] = Ts[x][yy];
}

// ---------------- relative-position bucket bias table ----------------
__device__ __forceinline__ int rel_bucket(int rel) {  // rel = k - q
  int ret = (rel > 0) ? 16 : 0;
  int rp = (rel < 0) ? -rel : rel;
  if (rp < 8) return ret + rp;
  int i = 0;
  i += (rp >= 12); i += (rp >= 16); i += (rp >= 23); i += (rp >= 32);
  i += (rp >= 46); i += (rp >= 64); i += (rp >= 91);
  return ret + 8 + i;
}

__global__ __launch_bounds__(256) void build_bias_rel(const float* __restrict__ tbl,
                                                      float* __restrict__ brel,
                                                      float* __restrict__ brel2) {
  int h = blockIdx.x;
  for (int rix = threadIdx.x; rix < 4095; rix += 256) {
    float v = tbl[rel_bucket(rix - 2047) * NHEAD + h];
    brel[h * 4096 + rix] = v;
    brel2[h * 4096 + rix] = v * LOG2E;   // exp2-domain copy for attention
  }
}

// ------- bf16 MFMA GEMM: C[M][N] = A[M][K] @ Bt[N][K]^T  (m97-style staging) -------
// XCD-bijective block swizzle (T1). If Vt != nullptr, columns >= 2048 (the V third
// of QKV) are written DIRECTLY in transposed Vt[bh*64+d][s] layout from the epilogue
// fragments (4 consecutive s per fragment -> one 8B store; lanes {quad} x i cover
// full 128B lines so L2 write-combines). This eliminates the transpose_v kernel.
__global__ __launch_bounds__(256) void gemm_bf16k(const u16* __restrict__ A,
                                                  const u16* __restrict__ Bt,
                                                  u16* __restrict__ Cb, float* __restrict__ Cf,
                                                  u16* __restrict__ Vt,
                                                  int M, int N, int K) {
  __shared__ u16 As[128 * 32];
  __shared__ u16 Bs[128 * 32];
  const int t = threadIdx.x;
  const int w = t >> 6, lane = t & 63, quad = lane >> 4, l15 = lane & 15;
  const int wr = w >> 1, wc = w & 1;

  const int nwg = gridDim.x * gridDim.y;
  const int orig = blockIdx.y * gridDim.x + blockIdx.x;
  const int wg = (orig & 7) * (nwg >> 3) + (orig >> 3);   // bijective: nwg % 8 == 0
  const int bx = wg % gridDim.x, by = wg / gridDim.x;
  const int row0 = by * 128, col0 = bx * 128;

  f32x4 acc[4][4];
  #pragma unroll
  for (int i = 0; i < 4; ++i)
    #pragma unroll
    for (int j = 0; j < 4; ++j) acc[i][j] = (f32x4){0.f, 0.f, 0.f, 0.f};

  const int srow = lane >> 2, scol = (lane & 3) * 8;

  for (int k0 = 0; k0 < K; k0 += 32) {
    #pragma unroll
    for (int p = 0; p < 2; ++p) {
      const int rb = w * 32 + p * 16;
      GLOAD_LDS16(&A[(size_t)(row0 + rb + srow) * K + k0 + scol], &As[rb * 32]);
      GLOAD_LDS16(&Bt[(size_t)(col0 + rb + srow) * K + k0 + scol], &Bs[rb * 32]);
    }
    __syncthreads();
    bf16x8 af[4], bfr[4];
    #pragma unroll
    for (int i = 0; i < 4; ++i)
      af[i] = *(const bf16x8*)&As[(wr * 64 + i * 16 + l15) * 32 + quad * 8];
    #pragma unroll
    for (int j = 0; j < 4; ++j)
      bfr[j] = *(const bf16x8*)&Bs[(wc * 64 + j * 16 + l15) * 32 + quad * 8];
    #pragma unroll
    for (int i = 0; i < 4; ++i)
      #pragma unroll
      for (int j = 0; j < 4; ++j)
        acc[i][j] = MFMA(af[i], bfr[j], acc[i][j]);
    __syncthreads();
  }
  #pragma unroll
  for (int i = 0; i < 4; ++i) {
    #pragma unroll
    for (int j = 0; j < 4; ++j) {
      const int col = col0 + wc * 64 + j * 16 + l15;
      const int srow0 = row0 + wr * 64 + i * 16 + quad * 4;
      if (Cf) {
        #pragma unroll
        for (int r = 0; r < 4; ++r)
          Cf[(size_t)(srow0 + r) * N + col] = acc[i][j][r];
      } else if (!Vt || col < 2 * DMODEL) {
        #pragma unroll
        for (int r = 0; r < 4; ++r)
          Cb[(size_t)(srow0 + r) * N + col] = f2bf(acc[i][j][r]);
      } else {
        // V third -> Vt[(b*16+h)*64+d][s], s = srow0..srow0+3 (8B contiguous)
        const int c2 = col - 2 * DMODEL, hh = c2 >> 6, dd = c2 & 63;
        const int bb = srow0 >> 11, ss = srow0 & (SEQ - 1);
        uint2 o;
        o.x = pkbf(acc[i][j][0], acc[i][j][1]);
        o.y = pkbf(acc[i][j][2], acc[i][j][3]);
        *(uint2*)&Vt[((size_t)(bb * 16 + hh) * 64 + dd) * SEQ + ss] = o;
      }
    }
  }
}

// ------------- fused flash attention (S^T, 32x32 MFMA, max-free softmax) -------------
// Block = 128 q-rows (4 waves x 32); K/V tile = 64 kpos, double-buffered LDS,
// one barrier per tile. T12: P assembled in-register via permlane32_swap.
// T1 XCD-chunked (qt,bh) remap (round 5: -15 us; round 7 PMC: FETCH 24.7 MB ~ ideal).
// OCCUPANCY (round 7 PMC): VGPR 132 > 128 cliff -> 3 blocks/CU resident out of a
// 4/CU grid -> 25% tail + Occupancy 10.8% with ALL pipes idle (Mfma 13%, VALU 28%,
// HBM 18%) = latency-bound. Fix: T15 dropped (PV reads V from LDS; -32 VGPR) and
// __launch_bounds__(256,4) pins VGPR <= 128 -> 4 waves/SIMD, 4 blocks/CU,
// full co-residency (LDS 36 KB x 4 = 144 <= 160 KB), zero tail.
// NOTE: plain (cached) stores for pos_bias are REQUIRED — nontemporal 16B stores
// defeat L2 write-combining and inflated HBM writes 3x (round 2: 824 MB vs 272 MB).
__global__ __launch_bounds__(256, 4) void attn_fused(const u16* __restrict__ QKV,
                                                     const u16* __restrict__ Vt,
                                                     const float* __restrict__ brel,
                                                     const float* __restrict__ brel2,
                                                     u16* __restrict__ Aout,
                                                     float* __restrict__ pb) {
  __shared__ u16 Ks[2][64 * 72];    // [buf][kpos][d]
  __shared__ u16 Vs[2][64 * 72];    // [buf][d][kpos]
  // T1-chunked remap (nwg = 16*64 = 1024, % 8 == 0 -> simple bijection)
  const int orig = blockIdx.y * gridDim.x + blockIdx.x;
  const int wg = (orig & 7) * 128 + (orig >> 3);
  const int qt = wg & 15, bh = wg >> 4;
  const int b = bh >> 4, h = bh & 15;
  const int t = threadIdx.x;
  const int w = t >> 6, lane = t & 63, l31 = lane & 31, h5 = lane >> 5;
  const int qb = qt * 128;          // block q-base
  const int qw0 = qb + w * 32;      // wave q-base
  const int qr = qw0 + l31;         // this lane's q-row

  const float cpos = brel2[h * 4096 + 4040];  // rel = +1993 (exp2 domain)
  const float cneg = brel2[h * 4096 + 54];    // rel = -1993
  const float cpu  = brel[h * 4096 + 4040];   // unscaled, for pos_bias
  const float cnu  = brel[h * 4096 + 54];

  // Q B-frags (loop-invariant): B[n=qr][k=d = ks*16 + h5*8 + i]
  const u16* qptr = QKV + (size_t)(b * SEQ + qr) * QKVN + h * 64 + h5 * 8;
  bf16x8 qf[4];
  #pragma unroll
  for (int ks = 0; ks < 4; ++ks) qf[ks] = *(const bf16x8*)(qptr + ks * 16);

  float lsum = 0.f;
  f32x16 oacc[2];
  #pragma unroll
  for (int m = 0; m < 2; ++m)
    #pragma unroll
    for (int i = 0; i < 16; ++i) oacc[m][i] = 0.f;

  const int c0 = t * 2, c1 = c0 + 1;
  const int r0s = c0 >> 3, cc0 = (c0 & 7) * 8;
  const int r1s = c1 >> 3, cc1 = (c1 & 7) * 8;
  const size_t krow = (size_t)(b * SEQ) * QKVN + DMODEL + h * 64;
  const size_t vtrow = (size_t)bh * 64;
  const float* brow = brel2 + h * 4096 + 2047;

  // prologue: tile 0 -> regs -> buf0
  uint4 ka0 = *(const uint4*)&QKV[krow + (size_t)r0s * QKVN + cc0];
  uint4 ka1 = *(const uint4*)&QKV[krow + (size_t)r1s * QKVN + cc1];
  uint4 va0 = *(const uint4*)&Vt[(vtrow + r0s) * SEQ + cc0];
  uint4 va1 = *(const uint4*)&Vt[(vtrow + r1s) * SEQ + cc1];
  *(uint4*)&Ks[0][r0s * 72 + cc0] = ka0;
  *(uint4*)&Ks[0][r1s * 72 + cc1] = ka1;
  *(uint4*)&Vs[0][r0s * 72 + cc0] = va0;
  *(uint4*)&Vs[0][r1s * 72 + cc1] = va1;
  __syncthreads();

  #pragma unroll 2
  for (int ti = 0; ti < SEQ / 64; ++ti) {
    const int kb = ti * 64;
    const int cur = ti & 1;
    const u16* Kc = Ks[cur];
    const u16* Vc = Vs[cur];

    // issue next tile's global loads (land during this tile's compute)
    if (ti + 1 < SEQ / 64) {
      ka0 = *(const uint4*)&QKV[krow + (size_t)(kb + 64 + r0s) * QKVN + cc0];
      ka1 = *(const uint4*)&QKV[krow + (size_t)(kb + 64 + r1s) * QKVN + cc1];
      va0 = *(const uint4*)&Vt[(vtrow + r0s) * SEQ + kb + 64 + cc0];
      va1 = *(const uint4*)&Vt[(vtrow + r1s) * SEQ + kb + 64 + cc1];
    }

    // S^T = K @ Q^T: two 32-kpos tiles, A = K-frag from LDS, B = Q regs
    f32x16 sc[2];
    __builtin_amdgcn_s_setprio(1);
    #pragma unroll
    for (int m = 0; m < 2; ++m) {
      #pragma unroll
      for (int i = 0; i < 16; ++i) sc[m][i] = 0.f;
      #pragma unroll
      for (int ks = 0; ks < 4; ++ks) {
        bf16x8 kf = *(const bf16x8*)&Kc[(m * 32 + l31) * 72 + ks * 16 + h5 * 8];
        sc[m] = MFMA32(kf, qf[ks], sc[m]);
      }
    }
    __builtin_amdgcn_s_setprio(0);

    // ---- fused pos_bias emission, spread: tiles ti == b (mod 4) ----
    if ((ti & 3) == b) {
      const int pr = qb + (t >> 1);
      const int pc = kb + (t & 1) * 32;
      float* po = pb + ((size_t)(h * SEQ + pr)) * SEQ + pc;
      const int lo = pc - pr;
      if (lo >= 91 || lo + 31 <= -91) {
        const float c = (lo >= 91) ? cpu : cnu;
        const float4 vv = {c, c, c, c};
        #pragma unroll
        for (int i = 0; i < 8; ++i) *(float4*)&po[i * 4] = vv;
      } else {
        const float* bb = brel + h * 4096 + 2047 - pr + pc;
        #pragma unroll
        for (int i = 0; i < 8; ++i) {
          float4 vv;
          vv.x = bb[i * 4]; vv.y = bb[i * 4 + 1];
          vv.z = bb[i * 4 + 2]; vv.w = bb[i * 4 + 3];
          *(float4*)&po[i * 4] = vv;
        }
      }
    }

    // bias + max-free softmax per 32-kpos tile; P packed in-register (T12)
    bf16x8 bp[4];
    #pragma unroll
    for (int m = 0; m < 2; ++m) {
      const int kb32 = kb + 32 * m;
      if (kb32 >= qw0 + 122) {              // whole tile rel >= 91
        #pragma unroll
        for (int i = 0; i < 16; ++i) sc[m][i] += cpos;
      } else if (kb32 <= qw0 - 122) {       // whole tile rel <= -91
        #pragma unroll
        for (int i = 0; i < 16; ++i) sc[m][i] += cneg;
      } else {
        const float* bb = brow + kb32 + 4 * h5 - qr;   // + (reg&3) + 8*(reg>>2)
        #pragma unroll
        for (int i = 0; i < 16; ++i) sc[m][i] += bb[(i & 3) + 8 * (i >> 2)];
      }
      u32 w0[4], w1[4];
      #pragma unroll
      for (int tt = 0; tt < 4; ++tt) {
        float p0 = exp2fast(sc[m][4 * tt + 0]);
        float p1 = exp2fast(sc[m][4 * tt + 1]);
        float p2 = exp2fast(sc[m][4 * tt + 2]);
        float p3 = exp2fast(sc[m][4 * tt + 3]);
        lsum += (p0 + p1) + (p2 + p3);
        w0[tt] = pkbf(p0, p1);
        w1[tt] = pkbf(p2, p3);
      }
      // cross-half exchange: each lane assembles its PV B-frag directly
      u32x2 r0 = plswap(w0[0], w0[1]);
      u32x2 r1 = plswap(w1[0], w1[1]);
      u32x2 r2 = plswap(w0[2], w0[3]);
      u32x2 r3 = plswap(w1[2], w1[3]);
      union { u32 u[4]; bf16x8 v; } q0, q1;
      q0.u[0] = r0.x; q0.u[1] = r1.x; q0.u[2] = r0.y; q0.u[3] = r1.y;
      q1.u[0] = r2.x; q1.u[1] = r3.x; q1.u[2] = r2.y; q1.u[3] = r3.y;
      bp[2 * m]     = q0.v;
      bp[2 * m + 1] = q1.v;
    }

    // PV: A = V-frag from LDS, B = in-register P frags
    __builtin_amdgcn_s_setprio(1);
    #pragma unroll
    for (int m2 = 0; m2 < 2; ++m2)
      #pragma unroll
      for (int ks = 0; ks < 4; ++ks) {
        bf16x8 vf = *(const bf16x8*)&Vc[(m2 * 32 + l31) * 72 + ks * 16 + h5 * 8];
        oacc[m2] = MFMA32(vf, bp[ks], oacc[m2]);
      }
    __builtin_amdgcn_s_setprio(0);

    // publish next tile into the other buffer (loads have landed by now)
    if (ti + 1 < SEQ / 64) {
      u16* Kn = Ks[cur ^ 1];
      u16* Vn = Vs[cur ^ 1];
      *(uint4*)&Kn[r0s * 72 + cc0] = ka0;
      *(uint4*)&Kn[r1s * 72 + cc1] = ka1;
      *(uint4*)&Vn[r0s * 72 + cc0] = va0;
      *(uint4*)&Vn[r1s * 72 + cc1] = va1;
    }
    __syncthreads();
  }

  // epilogue: lane holds O^T[d][qr]: d = 32*m2 + 8*tt + 4*h5 + (reg&3)
  lsum += __shfl_xor(lsum, 32);
  const float inv = 1.0f / lsum;
  const size_t rowb = (size_t)(b * SEQ + qr) * DMODEL + h * 64;
  #pragma unroll
  for (int m2 = 0; m2 < 2; ++m2)
    #pragma unroll
    for (int tt = 0; tt < 4; ++tt) {
      uint2 o;
      o.x = pkbf(oacc[m2][4 * tt + 0] * inv, oacc[m2][4 * tt + 1] * inv);
      o.y = pkbf(oacc[m2][4 * tt + 2] * inv, oacc[m2][4 * tt + 3] * inv);
      *(uint2*)&Aout[rowb + 32 * m2 + 8 * tt + 4 * h5] = o;
    }
}

extern "C" void kernel_launch(void* const* d_in, const int* in_sizes, int n_in,
                              void* d_out, int out_size, void* d_ws, size_t ws_size,
                              hipStream_t stream) {
  (void)in_sizes; (void)n_in; (void)out_size; (void)ws_size;
  const float* H   = (const float*)d_in[0];
  const float* Wq  = (const float*)d_in[1];
  const float* Wk  = (const float*)d_in[2];
  const float* Wv  = (const float*)d_in[3];
  const float* Wo  = (const float*)d_in[4];
  const float* tbl = (const float*)d_in[5];

  float* out = (float*)d_out;                       // [8192][1024] fp32
  float* pos_bias = out + (size_t)MROWS * DMODEL;   // [16][2048][2048] fp32

  char* ws = (char*)d_ws;
  u16* Hb     = (u16*)(ws);                 // 16 MB  (reused as attn_out later)
  u16* Wt     = (u16*)(ws + 16777216);      // 8 MB   [4096][1024]
  u16* QKV    = (u16*)(ws + 25165824);      // 48 MB  [8192][3072]
  u16* Vt     = (u16*)(ws + 75497472);      // 16 MB  [4096][2048]
  float* brel  = (float*)(ws + 92274688);   // 256 KB [16][4096]  (unscaled)
  float* brel2 = (float*)(ws + 92536832);   // 256 KB [16][4096]  (x log2e)

  convert_h<<<8192, 256, 0, stream>>>(H, Hb);
  transpose_w<<<dim3(32, 32, 4), dim3(32, 8), 0, stream>>>(Wq, Wk, Wv, Wo, Wt);
  build_bias_rel<<<16, 256, 0, stream>>>(tbl, brel, brel2);

  // QKV = Hb @ [Wq|Wk|Wv]; V third written directly transposed into Vt
  gemm_bf16k<<<dim3(QKVN / 128, MROWS / 128), 256, 0, stream>>>(
      Hb, Wt, QKV, nullptr, Vt, MROWS, QKVN, DMODEL);
  attn_fused<<<dim3(16, 64), 256, 0, stream>>>(QKV, Vt, brel, brel2,
                                               Hb /* attn_out */, pos_bias);
  // out = attn_out @ Wo   (fp32 out)
  gemm_bf16k<<<dim3(DMODEL / 128, MROWS / 128), 256, 0, stream>>>(
      Hb, Wt + (size_t)QKVN * DMODEL, nullptr, out, nullptr, MROWS, DMODEL, DMODEL);
}

// Round 9
// 570.815 us; speedup vs baseline: 1.4467x; 1.4467x over previous
//
#include <hip/hip_runtime.h>
#include <cstdint>
#include <cstddef>

typedef unsigned short u16;
typedef unsigned int u32;
typedef __attribute__((ext_vector_type(8))) short bf16x8;    // 8 bf16 in 4 VGPRs
typedef __attribute__((ext_vector_type(4))) float f32x4;
typedef __attribute__((ext_vector_type(16))) float f32x16;
typedef __attribute__((ext_vector_type(2))) unsigned int u32x2;

#define MFMA(a, b, c)   __builtin_amdgcn_mfma_f32_16x16x32_bf16((a), (b), (c), 0, 0, 0)
#define MFMA32(a, b, c) __builtin_amdgcn_mfma_f32_32x32x16_bf16((a), (b), (c), 0, 0, 0)

// async global->LDS, 16B per lane; LDS dest is wave-uniform base + lane*16
typedef const __attribute__((address_space(1))) void gv1_t;
typedef __attribute__((address_space(3))) void lv3_t;
#define GLOAD_LDS16(g, l) __builtin_amdgcn_global_load_lds((gv1_t*)(g), (lv3_t*)(l), 16, 0, 0)

#define BATCH 4
#define SEQ 2048
#define DMODEL 1024
#define NHEAD 16
#define MROWS (BATCH * SEQ)   // 8192
#define QKVN (3 * DMODEL)     // 3072

#define LOG2E 1.44269504088896340736f

// NOTE (round 7): inline-asm v_cvt_pk_bf16_f32 REGRESSED (+38 us total) — opaque
// to the scheduler in hot epilogues (m240 lesson confirmed). Keep integer RNE.
__device__ __forceinline__ u16 f2bf(float f) {
  u32 x = __builtin_bit_cast(u32, f);
  x += 0x7fffu + ((x >> 16) & 1u);   // RNE (values finite/normal here)
  return (u16)(x >> 16);
}

// RNE pack of two f32 -> packed bf16x2 (u32); lo = a, hi = b
__device__ __forceinline__ u32 pkbf(float a, float b) {
  return (u32)f2bf(a) | ((u32)f2bf(b) << 16);
}

// permlane32_swap: ret.x = [A(0:31), B(0:31)], ret.y = [A(32:63), B(32:63)]
__device__ __forceinline__ u32x2 plswap(u32 a, u32 b) {
  return __builtin_amdgcn_permlane32_swap(a, b, false, false);
}

extern "C" __device__ float __ocml_exp2_f32(float);
__device__ __forceinline__ float exp2fast(float x) {
#if __has_builtin(__builtin_amdgcn_exp2f)
  return __builtin_amdgcn_exp2f(x);
#else
  return __ocml_exp2_f32(x);
#endif
}

// ---------------- fp32 -> bf16 convert of hidden_states ----------------
__global__ __launch_bounds__(256) void convert_h(const float* __restrict__ H,
                                                 u16* __restrict__ Hb) {
  size_t i = (size_t)blockIdx.x * 1024 + threadIdx.x * 4;
  float4 v = *(const float4*)&H[i];
  uint2 o;
  o.x = pkbf(v.x, v.y);
  o.y = pkbf(v.z, v.w);
  *(uint2*)&Hb[i] = o;
}

// ------------- transpose + convert Wq|Wk|Wv|Wo -> Wt[4096][1024] -------------
// Wq is pre-scaled by log2(e) so attention scores land in the exp2 domain.
__global__ void transpose_w(const float* __restrict__ Wq, const float* __restrict__ Wk,
                            const float* __restrict__ Wv, const float* __restrict__ Wo,
                            u16* __restrict__ Wt) {
  __shared__ u16 Ts[32][33];
  const float* W = (blockIdx.z == 0) ? Wq : (blockIdx.z == 1) ? Wk
                   : (blockIdx.z == 2) ? Wv : Wo;
  const float s = (blockIdx.z == 0) ? LOG2E : 1.0f;
  int x = threadIdx.x, y0 = threadIdx.y;
  int r0 = blockIdx.y * 32, c0 = blockIdx.x * 32;
  for (int yy = y0; yy < 32; yy += 8)
    Ts[yy][x] = f2bf(W[(size_t)(r0 + yy) * 1024 + c0 + x] * s);
  __syncthreads();
  for (int yy = y0; yy < 32; yy += 8)
    Wt[(size_t)(blockIdx.z * 1024 + c0 + yy) * 1024 + r0 + x] = Ts[x][yy];
}

// ---------------- relative-position bucket bias table ----------------
__device__ __forceinline__ int rel_bucket(int rel) {  // rel = k - q
  int ret = (rel > 0) ? 16 : 0;
  int rp = (rel < 0) ? -rel : rel;
  if (rp < 8) return ret + rp;
  int i = 0;
  i += (rp >= 12); i += (rp >= 16); i += (rp >= 23); i += (rp >= 32);
  i += (rp >= 46); i += (rp >= 64); i += (rp >= 91);
  return ret + 8 + i;
}

__global__ __launch_bounds__(256) void build_bias_rel(const float* __restrict__ tbl,
                                                      float* __restrict__ brel,
                                                      float* __restrict__ brel2) {
  int h = blockIdx.x;
  for (int rix = threadIdx.x; rix < 4095; rix += 256) {
    float v = tbl[rel_bucket(rix - 2047) * NHEAD + h];
    brel[h * 4096 + rix] = v;
    brel2[h * 4096 + rix] = v * LOG2E;   // exp2-domain copy for attention
  }
}

// ------- bf16 MFMA GEMM: C[M][N] = A[M][K] @ Bt[N][K]^T  (m97-style staging) -------
// XCD-bijective block swizzle (T1). If Vt != nullptr, columns >= 2048 (the V third
// of QKV) are written DIRECTLY in transposed Vt[bh*64+d][s] layout from the epilogue
// fragments (4 consecutive s per fragment -> one 8B store; lanes {quad} x i cover
// full 128B lines so L2 write-combines). This eliminates the transpose_v kernel.
__global__ __launch_bounds__(256) void gemm_bf16k(const u16* __restrict__ A,
                                                  const u16* __restrict__ Bt,
                                                  u16* __restrict__ Cb, float* __restrict__ Cf,
                                                  u16* __restrict__ Vt,
                                                  int M, int N, int K) {
  __shared__ u16 As[128 * 32];
  __shared__ u16 Bs[128 * 32];
  const int t = threadIdx.x;
  const int w = t >> 6, lane = t & 63, quad = lane >> 4, l15 = lane & 15;
  const int wr = w >> 1, wc = w & 1;

  const int nwg = gridDim.x * gridDim.y;
  const int orig = blockIdx.y * gridDim.x + blockIdx.x;
  const int wg = (orig & 7) * (nwg >> 3) + (orig >> 3);   // bijective: nwg % 8 == 0
  const int bx = wg % gridDim.x, by = wg / gridDim.x;
  const int row0 = by * 128, col0 = bx * 128;

  f32x4 acc[4][4];
  #pragma unroll
  for (int i = 0; i < 4; ++i)
    #pragma unroll
    for (int j = 0; j < 4; ++j) acc[i][j] = (f32x4){0.f, 0.f, 0.f, 0.f};

  const int srow = lane >> 2, scol = (lane & 3) * 8;

  for (int k0 = 0; k0 < K; k0 += 32) {
    #pragma unroll
    for (int p = 0; p < 2; ++p) {
      const int rb = w * 32 + p * 16;
      GLOAD_LDS16(&A[(size_t)(row0 + rb + srow) * K + k0 + scol], &As[rb * 32]);
      GLOAD_LDS16(&Bt[(size_t)(col0 + rb + srow) * K + k0 + scol], &Bs[rb * 32]);
    }
    __syncthreads();
    bf16x8 af[4], bfr[4];
    #pragma unroll
    for (int i = 0; i < 4; ++i)
      af[i] = *(const bf16x8*)&As[(wr * 64 + i * 16 + l15) * 32 + quad * 8];
    #pragma unroll
    for (int j = 0; j < 4; ++j)
      bfr[j] = *(const bf16x8*)&Bs[(wc * 64 + j * 16 + l15) * 32 + quad * 8];
    #pragma unroll
    for (int i = 0; i < 4; ++i)
      #pragma unroll
      for (int j = 0; j < 4; ++j)
        acc[i][j] = MFMA(af[i], bfr[j], acc[i][j]);
    __syncthreads();
  }
  #pragma unroll
  for (int i = 0; i < 4; ++i) {
    #pragma unroll
    for (int j = 0; j < 4; ++j) {
      const int col = col0 + wc * 64 + j * 16 + l15;
      const int srow0 = row0 + wr * 64 + i * 16 + quad * 4;
      if (Cf) {
        #pragma unroll
        for (int r = 0; r < 4; ++r)
          Cf[(size_t)(srow0 + r) * N + col] = acc[i][j][r];
      } else if (!Vt || col < 2 * DMODEL) {
        #pragma unroll
        for (int r = 0; r < 4; ++r)
          Cb[(size_t)(srow0 + r) * N + col] = f2bf(acc[i][j][r]);
      } else {
        // V third -> Vt[(b*16+h)*64+d][s], s = srow0..srow0+3 (8B contiguous)
        const int c2 = col - 2 * DMODEL, hh = c2 >> 6, dd = c2 & 63;
        const int bb = srow0 >> 11, ss = srow0 & (SEQ - 1);
        uint2 o;
        o.x = pkbf(acc[i][j][0], acc[i][j][1]);
        o.y = pkbf(acc[i][j][2], acc[i][j][3]);
        *(uint2*)&Vt[((size_t)(bb * 16 + hh) * 64 + dd) * SEQ + ss] = o;
      }
    }
  }
}

// ------------- fused flash attention (S^T, 32x32 MFMA, max-free softmax) -------------
// Block = 128 q-rows (4 waves x 32); K/V tile = 64 kpos, double-buffered LDS,
// one barrier per tile. T12: P assembled in-register via permlane32_swap.
// T1 XCD-chunked (qt,bh) remap (round 7 PMC: FETCH 24.7 MB ~ ideal).
// VGPR HISTORY: r7 = 132 VGPR (T15) -> 3 blk/CU, Occ 10.8%, latency-bound @215us.
// r8 = __launch_bounds__(256,4) forced VGPR to 64 -> MASSIVE scratch spills
// (FETCH 665 MB, WRITE 998 MB) @424us. NEVER force the min-waves arg here.
// This round: get under the 128 cliff organically — no T15, plain bounds, and the
// tile body is restructured per-32-kpos-half {QK(m) -> SM(m)} so only ONE f32x16
// score block is live at a time (-16 VGPR). QK(m=1) is independent of SM(m=0) so
// the scheduler can still overlap MFMA with softmax VALU.
// NOTE: plain (cached) stores for pos_bias are REQUIRED — nontemporal 16B stores
// defeat L2 write-combining and inflated HBM writes 3x (round 2: 824 MB vs 272 MB).
__global__ __launch_bounds__(256) void attn_fused(const u16* __restrict__ QKV,
                                                  const u16* __restrict__ Vt,
                                                  const float* __restrict__ brel,
                                                  const float* __restrict__ brel2,
                                                  u16* __restrict__ Aout,
                                                  float* __restrict__ pb) {
  __shared__ u16 Ks[2][64 * 72];    // [buf][kpos][d]
  __shared__ u16 Vs[2][64 * 72];    // [buf][d][kpos]
  // T1-chunked remap (nwg = 16*64 = 1024, % 8 == 0 -> simple bijection)
  const int orig = blockIdx.y * gridDim.x + blockIdx.x;
  const int wg = (orig & 7) * 128 + (orig >> 3);
  const int qt = wg & 15, bh = wg >> 4;
  const int b = bh >> 4, h = bh & 15;
  const int t = threadIdx.x;
  const int w = t >> 6, lane = t & 63, l31 = lane & 31, h5 = lane >> 5;
  const int qb = qt * 128;          // block q-base
  const int qw0 = qb + w * 32;      // wave q-base
  const int qr = qw0 + l31;         // this lane's q-row

  const float cpos = brel2[h * 4096 + 4040];  // rel = +1993 (exp2 domain)
  const float cneg = brel2[h * 4096 + 54];    // rel = -1993
  const float cpu  = brel[h * 4096 + 4040];   // unscaled, for pos_bias
  const float cnu  = brel[h * 4096 + 54];

  // Q B-frags (loop-invariant): B[n=qr][k=d = ks*16 + h5*8 + i]
  const u16* qptr = QKV + (size_t)(b * SEQ + qr) * QKVN + h * 64 + h5 * 8;
  bf16x8 qf[4];
  #pragma unroll
  for (int ks = 0; ks < 4; ++ks) qf[ks] = *(const bf16x8*)(qptr + ks * 16);

  float lsum = 0.f;
  f32x16 oacc[2];
  #pragma unroll
  for (int m = 0; m < 2; ++m)
    #pragma unroll
    for (int i = 0; i < 16; ++i) oacc[m][i] = 0.f;

  const int c0 = t * 2, c1 = c0 + 1;
  const int r0s = c0 >> 3, cc0 = (c0 & 7) * 8;
  const int r1s = c1 >> 3, cc1 = (c1 & 7) * 8;
  const size_t krow = (size_t)(b * SEQ) * QKVN + DMODEL + h * 64;
  const size_t vtrow = (size_t)bh * 64;
  const float* brow = brel2 + h * 4096 + 2047;

  // prologue: tile 0 -> regs -> buf0
  uint4 ka0 = *(const uint4*)&QKV[krow + (size_t)r0s * QKVN + cc0];
  uint4 ka1 = *(const uint4*)&QKV[krow + (size_t)r1s * QKVN + cc1];
  uint4 va0 = *(const uint4*)&Vt[(vtrow + r0s) * SEQ + cc0];
  uint4 va1 = *(const uint4*)&Vt[(vtrow + r1s) * SEQ + cc1];
  *(uint4*)&Ks[0][r0s * 72 + cc0] = ka0;
  *(uint4*)&Ks[0][r1s * 72 + cc1] = ka1;
  *(uint4*)&Vs[0][r0s * 72 + cc0] = va0;
  *(uint4*)&Vs[0][r1s * 72 + cc1] = va1;
  __syncthreads();

  #pragma unroll 2
  for (int ti = 0; ti < SEQ / 64; ++ti) {
    const int kb = ti * 64;
    const int cur = ti & 1;
    const u16* Kc = Ks[cur];
    const u16* Vc = Vs[cur];

    // issue next tile's global loads (land during this tile's compute)
    if (ti + 1 < SEQ / 64) {
      ka0 = *(const uint4*)&QKV[krow + (size_t)(kb + 64 + r0s) * QKVN + cc0];
      ka1 = *(const uint4*)&QKV[krow + (size_t)(kb + 64 + r1s) * QKVN + cc1];
      va0 = *(const uint4*)&Vt[(vtrow + r0s) * SEQ + kb + 64 + cc0];
      va1 = *(const uint4*)&Vt[(vtrow + r1s) * SEQ + kb + 64 + cc1];
    }

    // per-32-kpos half: QK(m) -> bias -> softmax -> bp (one f32x16 live)
    bf16x8 bp[4];
    #pragma unroll
    for (int m = 0; m < 2; ++m) {
      f32x16 sc;
      #pragma unroll
      for (int i = 0; i < 16; ++i) sc[i] = 0.f;
      __builtin_amdgcn_s_setprio(1);
      #pragma unroll
      for (int ks = 0; ks < 4; ++ks) {
        bf16x8 kf = *(const bf16x8*)&Kc[(m * 32 + l31) * 72 + ks * 16 + h5 * 8];
        sc = MFMA32(kf, qf[ks], sc);
      }
      __builtin_amdgcn_s_setprio(0);

      // fused pos_bias emission under QK(0)'s MFMA latency; tiles ti == b (mod 4)
      if (m == 0 && (ti & 3) == b) {
        const int pr = qb + (t >> 1);
        const int pc = kb + (t & 1) * 32;
        float* po = pb + ((size_t)(h * SEQ + pr)) * SEQ + pc;
        const int lo = pc - pr;
        if (lo >= 91 || lo + 31 <= -91) {
          const float c = (lo >= 91) ? cpu : cnu;
          const float4 vv = {c, c, c, c};
          #pragma unroll
          for (int i = 0; i < 8; ++i) *(float4*)&po[i * 4] = vv;
        } else {
          const float* bb = brel + h * 4096 + 2047 - pr + pc;
          #pragma unroll
          for (int i = 0; i < 8; ++i) {
            float4 vv;
            vv.x = bb[i * 4]; vv.y = bb[i * 4 + 1];
            vv.z = bb[i * 4 + 2]; vv.w = bb[i * 4 + 3];
            *(float4*)&po[i * 4] = vv;
          }
        }
      }

      const int kb32 = kb + 32 * m;
      if (kb32 >= qw0 + 122) {              // whole tile rel >= 91
        #pragma unroll
        for (int i = 0; i < 16; ++i) sc[i] += cpos;
      } else if (kb32 <= qw0 - 122) {       // whole tile rel <= -91
        #pragma unroll
        for (int i = 0; i < 16; ++i) sc[i] += cneg;
      } else {
        const float* bb = brow + kb32 + 4 * h5 - qr;   // + (reg&3) + 8*(reg>>2)
        #pragma unroll
        for (int i = 0; i < 16; ++i) sc[i] += bb[(i & 3) + 8 * (i >> 2)];
      }
      u32 w0[4], w1[4];
      #pragma unroll
      for (int tt = 0; tt < 4; ++tt) {
        float p0 = exp2fast(sc[4 * tt + 0]);
        float p1 = exp2fast(sc[4 * tt + 1]);
        float p2 = exp2fast(sc[4 * tt + 2]);
        float p3 = exp2fast(sc[4 * tt + 3]);
        lsum += (p0 + p1) + (p2 + p3);
        w0[tt] = pkbf(p0, p1);
        w1[tt] = pkbf(p2, p3);
      }
      // cross-half exchange: each lane assembles its PV B-frag directly
      u32x2 r0 = plswap(w0[0], w0[1]);
      u32x2 r1 = plswap(w1[0], w1[1]);
      u32x2 r2 = plswap(w0[2], w0[3]);
      u32x2 r3 = plswap(w1[2], w1[3]);
      union { u32 u[4]; bf16x8 v; } q0, q1;
      q0.u[0] = r0.x; q0.u[1] = r1.x; q0.u[2] = r0.y; q0.u[3] = r1.y;
      q1.u[0] = r2.x; q1.u[1] = r3.x; q1.u[2] = r2.y; q1.u[3] = r3.y;
      bp[2 * m]     = q0.v;
      bp[2 * m + 1] = q1.v;
    }

    // PV: A = V-frag from LDS, B = in-register P frags
    __builtin_amdgcn_s_setprio(1);
    #pragma unroll
    for (int m2 = 0; m2 < 2; ++m2)
      #pragma unroll
      for (int ks = 0; ks < 4; ++ks) {
        bf16x8 vf = *(const bf16x8*)&Vc[(m2 * 32 + l31) * 72 + ks * 16 + h5 * 8];
        oacc[m2] = MFMA32(vf, bp[ks], oacc[m2]);
      }
    __builtin_amdgcn_s_setprio(0);

    // publish next tile into the other buffer (loads have landed by now)
    if (ti + 1 < SEQ / 64) {
      u16* Kn = Ks[cur ^ 1];
      u16* Vn = Vs[cur ^ 1];
      *(uint4*)&Kn[r0s * 72 + cc0] = ka0;
      *(uint4*)&Kn[r1s * 72 + cc1] = ka1;
      *(uint4*)&Vn[r0s * 72 + cc0] = va0;
      *(uint4*)&Vn[r1s * 72 + cc1] = va1;
    }
    __syncthreads();
  }

  // epilogue: lane holds O^T[d][qr]: d = 32*m2 + 8*tt + 4*h5 + (reg&3)
  lsum += __shfl_xor(lsum, 32);
  const float inv = 1.0f / lsum;
  const size_t rowb = (size_t)(b * SEQ + qr) * DMODEL + h * 64;
  #pragma unroll
  for (int m2 = 0; m2 < 2; ++m2)
    #pragma unroll
    for (int tt = 0; tt < 4; ++tt) {
      uint2 o;
      o.x = pkbf(oacc[m2][4 * tt + 0] * inv, oacc[m2][4 * tt + 1] * inv);
      o.y = pkbf(oacc[m2][4 * tt + 2] * inv, oacc[m2][4 * tt + 3] * inv);
      *(uint2*)&Aout[rowb + 32 * m2 + 8 * tt + 4 * h5] = o;
    }
}

extern "C" void kernel_launch(void* const* d_in, const int* in_sizes, int n_in,
                              void* d_out, int out_size, void* d_ws, size_t ws_size,
                              hipStream_t stream) {
  (void)in_sizes; (void)n_in; (void)out_size; (void)ws_size;
  const float* H   = (const float*)d_in[0];
  const float* Wq  = (const float*)d_in[1];
  const float* Wk  = (const float*)d_in[2];
  const float* Wv  = (const float*)d_in[3];
  const float* Wo  = (const float*)d_in[4];
  const float* tbl = (const float*)d_in[5];

  float* out = (float*)d_out;                       // [8192][1024] fp32
  float* pos_bias = out + (size_t)MROWS * DMODEL;   // [16][2048][2048] fp32

  char* ws = (char*)d_ws;
  u16* Hb     = (u16*)(ws);                 // 16 MB  (reused as attn_out later)
  u16* Wt     = (u16*)(ws + 16777216);      // 8 MB   [4096][1024]
  u16* QKV    = (u16*)(ws + 25165824);      // 48 MB  [8192][3072]
  u16* Vt     = (u16*)(ws + 75497472);      // 16 MB  [4096][2048]
  float* brel  = (float*)(ws + 92274688);   // 256 KB [16][4096]  (unscaled)
  float* brel2 = (float*)(ws + 92536832);   // 256 KB [16][4096]  (x log2e)

  convert_h<<<8192, 256, 0, stream>>>(H, Hb);
  transpose_w<<<dim3(32, 32, 4), dim3(32, 8), 0, stream>>>(Wq, Wk, Wv, Wo, Wt);
  build_bias_rel<<<16, 256, 0, stream>>>(tbl, brel, brel2);

  // QKV = Hb @ [Wq|Wk|Wv]; V third written directly transposed into Vt
  gemm_bf16k<<<dim3(QKVN / 128, MROWS / 128), 256, 0, stream>>>(
      Hb, Wt, QKV, nullptr, Vt, MROWS, QKVN, DMODEL);
  attn_fused<<<dim3(16, 64), 256, 0, stream>>>(QKV, Vt, brel, brel2,
                                               Hb /* attn_out */, pos_bias);
  // out = attn_out @ Wo   (fp32 out)
  gemm_bf16k<<<dim3(DMODEL / 128, MROWS / 128), 256, 0, stream>>>(
      Hb, Wt + (size_t)QKVN * DMODEL, nullptr, out, nullptr, MROWS, DMODEL, DMODEL);
}

// Round 10
// 558.683 us; speedup vs baseline: 1.4781x; 1.0217x over previous
//
#include <hip/hip_runtime.h>
#include <cstdint>
#include <cstddef>

typedef unsigned short u16;
typedef unsigned int u32;
typedef __attribute__((ext_vector_type(8))) short bf16x8;    // 8 bf16 in 4 VGPRs
typedef __attribute__((ext_vector_type(4))) float f32x4;
typedef __attribute__((ext_vector_type(16))) float f32x16;
typedef __attribute__((ext_vector_type(2))) unsigned int u32x2;

#define MFMA(a, b, c)   __builtin_amdgcn_mfma_f32_16x16x32_bf16((a), (b), (c), 0, 0, 0)
#define MFMA32(a, b, c) __builtin_amdgcn_mfma_f32_32x32x16_bf16((a), (b), (c), 0, 0, 0)

// async global->LDS, 16B per lane; LDS dest is wave-uniform base + lane*16
typedef const __attribute__((address_space(1))) void gv1_t;
typedef __attribute__((address_space(3))) void lv3_t;
#define GLOAD_LDS16(g, l) __builtin_amdgcn_global_load_lds((gv1_t*)(g), (lv3_t*)(l), 16, 0, 0)

#define BATCH 4
#define SEQ 2048
#define DMODEL 1024
#define NHEAD 16
#define MROWS (BATCH * SEQ)   // 8192
#define QKVN (3 * DMODEL)     // 3072

#define LOG2E 1.44269504088896340736f

// NOTE (round 7): inline-asm v_cvt_pk_bf16_f32 REGRESSED (+38 us total) — opaque
// to the scheduler in hot epilogues (m240 lesson confirmed). Keep integer RNE
// for cold paths.
__device__ __forceinline__ u16 f2bf(float f) {
  u32 x = __builtin_bit_cast(u32, f);
  x += 0x7fffu + ((x >> 16) & 1u);   // RNE (values finite/normal here)
  return (u16)(x >> 16);
}

// RNE pack of two f32 -> packed bf16x2 (u32); lo = a, hi = b
__device__ __forceinline__ u32 pkbf(float a, float b) {
  return (u32)f2bf(a) | ((u32)f2bf(b) << 16);
}

// FAST pack (attn hot loop only): round-half-up + v_perm_b32 byte select.
// 3 VALU ops vs ~10 for RNE; differs from RNE only on exact ties (low16==0x8000,
// measure-zero for exp2 outputs; <=1 ulp when it happens). Builtin (not asm) so
// the scheduler still sees and interleaves it (round-7 lesson).
__device__ __forceinline__ u32 pkbf_fast(float a, float b) {
  u32 au = __builtin_bit_cast(u32, a) + 0x8000u;
  u32 bu = __builtin_bit_cast(u32, b) + 0x8000u;
  return __builtin_amdgcn_perm(bu, au, 0x07060302u);  // [b.hi16 | a.hi16]
}

// permlane32_swap: ret.x = [A(0:31), B(0:31)], ret.y = [A(32:63), B(32:63)]
__device__ __forceinline__ u32x2 plswap(u32 a, u32 b) {
  return __builtin_amdgcn_permlane32_swap(a, b, false, false);
}

extern "C" __device__ float __ocml_exp2_f32(float);
__device__ __forceinline__ float exp2fast(float x) {
#if __has_builtin(__builtin_amdgcn_exp2f)
  return __builtin_amdgcn_exp2f(x);
#else
  return __ocml_exp2_f32(x);
#endif
}

// ---------------- fp32 -> bf16 convert of hidden_states ----------------
__global__ __launch_bounds__(256) void convert_h(const float* __restrict__ H,
                                                 u16* __restrict__ Hb) {
  size_t i = (size_t)blockIdx.x * 1024 + threadIdx.x * 4;
  float4 v = *(const float4*)&H[i];
  uint2 o;
  o.x = pkbf(v.x, v.y);
  o.y = pkbf(v.z, v.w);
  *(uint2*)&Hb[i] = o;
}

// ------------- transpose + convert Wq|Wk|Wv|Wo -> Wt[4096][1024] -------------
// Wq is pre-scaled by log2(e) so attention scores land in the exp2 domain.
__global__ void transpose_w(const float* __restrict__ Wq, const float* __restrict__ Wk,
                            const float* __restrict__ Wv, const float* __restrict__ Wo,
                            u16* __restrict__ Wt) {
  __shared__ u16 Ts[32][33];
  const float* W = (blockIdx.z == 0) ? Wq : (blockIdx.z == 1) ? Wk
                   : (blockIdx.z == 2) ? Wv : Wo;
  const float s = (blockIdx.z == 0) ? LOG2E : 1.0f;
  int x = threadIdx.x, y0 = threadIdx.y;
  int r0 = blockIdx.y * 32, c0 = blockIdx.x * 32;
  for (int yy = y0; yy < 32; yy += 8)
    Ts[yy][x] = f2bf(W[(size_t)(r0 + yy) * 1024 + c0 + x] * s);
  __syncthreads();
  for (int yy = y0; yy < 32; yy += 8)
    Wt[(size_t)(blockIdx.z * 1024 + c0 + yy) * 1024 + r0 + x] = Ts[x][yy];
}

// ---------------- relative-position bucket bias table ----------------
__device__ __forceinline__ int rel_bucket(int rel) {  // rel = k - q
  int ret = (rel > 0) ? 16 : 0;
  int rp = (rel < 0) ? -rel : rel;
  if (rp < 8) return ret + rp;
  int i = 0;
  i += (rp >= 12); i += (rp >= 16); i += (rp >= 23); i += (rp >= 32);
  i += (rp >= 46); i += (rp >= 64); i += (rp >= 91);
  return ret + 8 + i;
}

__global__ __launch_bounds__(256) void build_bias_rel(const float* __restrict__ tbl,
                                                      float* __restrict__ brel,
                                                      float* __restrict__ brel2) {
  int h = blockIdx.x;
  for (int rix = threadIdx.x; rix < 4095; rix += 256) {
    float v = tbl[rel_bucket(rix - 2047) * NHEAD + h];
    brel[h * 4096 + rix] = v;
    brel2[h * 4096 + rix] = v * LOG2E;   // exp2-domain copy for attention
  }
}

// ------- bf16 MFMA GEMM: C[M][N] = A[M][K] @ Bt[N][K]^T  (m97-style staging) -------
// XCD-bijective block swizzle (T1). If Vt != nullptr, columns >= 2048 (the V third
// of QKV) are written DIRECTLY in transposed Vt[bh*64+d][s] layout from the epilogue
// fragments (4 consecutive s per fragment -> one 8B store; lanes {quad} x i cover
// full 128B lines so L2 write-combines). This eliminates the transpose_v kernel.
__global__ __launch_bounds__(256) void gemm_bf16k(const u16* __restrict__ A,
                                                  const u16* __restrict__ Bt,
                                                  u16* __restrict__ Cb, float* __restrict__ Cf,
                                                  u16* __restrict__ Vt,
                                                  int M, int N, int K) {
  __shared__ u16 As[128 * 32];
  __shared__ u16 Bs[128 * 32];
  const int t = threadIdx.x;
  const int w = t >> 6, lane = t & 63, quad = lane >> 4, l15 = lane & 15;
  const int wr = w >> 1, wc = w & 1;

  const int nwg = gridDim.x * gridDim.y;
  const int orig = blockIdx.y * gridDim.x + blockIdx.x;
  const int wg = (orig & 7) * (nwg >> 3) + (orig >> 3);   // bijective: nwg % 8 == 0
  const int bx = wg % gridDim.x, by = wg / gridDim.x;
  const int row0 = by * 128, col0 = bx * 128;

  f32x4 acc[4][4];
  #pragma unroll
  for (int i = 0; i < 4; ++i)
    #pragma unroll
    for (int j = 0; j < 4; ++j) acc[i][j] = (f32x4){0.f, 0.f, 0.f, 0.f};

  const int srow = lane >> 2, scol = (lane & 3) * 8;

  for (int k0 = 0; k0 < K; k0 += 32) {
    #pragma unroll
    for (int p = 0; p < 2; ++p) {
      const int rb = w * 32 + p * 16;
      GLOAD_LDS16(&A[(size_t)(row0 + rb + srow) * K + k0 + scol], &As[rb * 32]);
      GLOAD_LDS16(&Bt[(size_t)(col0 + rb + srow) * K + k0 + scol], &Bs[rb * 32]);
    }
    __syncthreads();
    bf16x8 af[4], bfr[4];
    #pragma unroll
    for (int i = 0; i < 4; ++i)
      af[i] = *(const bf16x8*)&As[(wr * 64 + i * 16 + l15) * 32 + quad * 8];
    #pragma unroll
    for (int j = 0; j < 4; ++j)
      bfr[j] = *(const bf16x8*)&Bs[(wc * 64 + j * 16 + l15) * 32 + quad * 8];
    #pragma unroll
    for (int i = 0; i < 4; ++i)
      #pragma unroll
      for (int j = 0; j < 4; ++j)
        acc[i][j] = MFMA(af[i], bfr[j], acc[i][j]);
    __syncthreads();
  }
  #pragma unroll
  for (int i = 0; i < 4; ++i) {
    #pragma unroll
    for (int j = 0; j < 4; ++j) {
      const int col = col0 + wc * 64 + j * 16 + l15;
      const int srow0 = row0 + wr * 64 + i * 16 + quad * 4;
      if (Cf) {
        #pragma unroll
        for (int r = 0; r < 4; ++r)
          Cf[(size_t)(srow0 + r) * N + col] = acc[i][j][r];
      } else if (!Vt || col < 2 * DMODEL) {
        #pragma unroll
        for (int r = 0; r < 4; ++r)
          Cb[(size_t)(srow0 + r) * N + col] = f2bf(acc[i][j][r]);
      } else {
        // V third -> Vt[(b*16+h)*64+d][s], s = srow0..srow0+3 (8B contiguous)
        const int c2 = col - 2 * DMODEL, hh = c2 >> 6, dd = c2 & 63;
        const int bb = srow0 >> 11, ss = srow0 & (SEQ - 1);
        uint2 o;
        o.x = pkbf(acc[i][j][0], acc[i][j][1]);
        o.y = pkbf(acc[i][j][2], acc[i][j][3]);
        *(uint2*)&Vt[((size_t)(bb * 16 + hh) * 64 + dd) * SEQ + ss] = o;
      }
    }
  }
}

// ------------- fused flash attention (S^T, 32x32 MFMA, max-free softmax) -------------
// Block = 128 q-rows (4 waves x 32); K/V tile = 64 kpos, double-buffered LDS,
// one barrier per tile. T12: P assembled in-register via permlane32_swap.
// T1 XCD-chunked (qt,bh) remap (round 7 PMC: FETCH 24.7 MB ~ ideal).
// VGPR HISTORY: r7 = 132 VGPR (T15) -> 3 blk/CU, Occ 10.8%, latency-bound @215us.
// r8 = __launch_bounds__(256,4) forced VGPR to 64 -> MASSIVE scratch spills
// (FETCH 665 MB, WRITE 998 MB) @424us. NEVER force the min-waves arg here.
// r9 = per-32-kpos-half restructure {QK(m) -> SM(m)}: one f32x16 live at a time.
// r10 (this): pkbf_fast (v_perm, 3 ops) for the inner-loop P packing — packing was
// ~16x10 = the largest VALU consumer/tile (r7 PMC: VALU-busy 60us > MFMA 28us).
// NOTE: plain (cached) stores for pos_bias are REQUIRED — nontemporal 16B stores
// defeat L2 write-combining and inflated HBM writes 3x (round 2: 824 MB vs 272 MB).
__global__ __launch_bounds__(256) void attn_fused(const u16* __restrict__ QKV,
                                                  const u16* __restrict__ Vt,
                                                  const float* __restrict__ brel,
                                                  const float* __restrict__ brel2,
                                                  u16* __restrict__ Aout,
                                                  float* __restrict__ pb) {
  __shared__ u16 Ks[2][64 * 72];    // [buf][kpos][d]
  __shared__ u16 Vs[2][64 * 72];    // [buf][d][kpos]
  // T1-chunked remap (nwg = 16*64 = 1024, % 8 == 0 -> simple bijection)
  const int orig = blockIdx.y * gridDim.x + blockIdx.x;
  const int wg = (orig & 7) * 128 + (orig >> 3);
  const int qt = wg & 15, bh = wg >> 4;
  const int b = bh >> 4, h = bh & 15;
  const int t = threadIdx.x;
  const int w = t >> 6, lane = t & 63, l31 = lane & 31, h5 = lane >> 5;
  const int qb = qt * 128;          // block q-base
  const int qw0 = qb + w * 32;      // wave q-base
  const int qr = qw0 + l31;         // this lane's q-row

  const float cpos = brel2[h * 4096 + 4040];  // rel = +1993 (exp2 domain)
  const float cneg = brel2[h * 4096 + 54];    // rel = -1993
  const float cpu  = brel[h * 4096 + 4040];   // unscaled, for pos_bias
  const float cnu  = brel[h * 4096 + 54];

  // Q B-frags (loop-invariant): B[n=qr][k=d = ks*16 + h5*8 + i]
  const u16* qptr = QKV + (size_t)(b * SEQ + qr) * QKVN + h * 64 + h5 * 8;
  bf16x8 qf[4];
  #pragma unroll
  for (int ks = 0; ks < 4; ++ks) qf[ks] = *(const bf16x8*)(qptr + ks * 16);

  float lsum = 0.f;
  f32x16 oacc[2];
  #pragma unroll
  for (int m = 0; m < 2; ++m)
    #pragma unroll
    for (int i = 0; i < 16; ++i) oacc[m][i] = 0.f;

  const int c0 = t * 2, c1 = c0 + 1;
  const int r0s = c0 >> 3, cc0 = (c0 & 7) * 8;
  const int r1s = c1 >> 3, cc1 = (c1 & 7) * 8;
  const size_t krow = (size_t)(b * SEQ) * QKVN + DMODEL + h * 64;
  const size_t vtrow = (size_t)bh * 64;
  const float* brow = brel2 + h * 4096 + 2047;

  // prologue: tile 0 -> regs -> buf0
  uint4 ka0 = *(const uint4*)&QKV[krow + (size_t)r0s * QKVN + cc0];
  uint4 ka1 = *(const uint4*)&QKV[krow + (size_t)r1s * QKVN + cc1];
  uint4 va0 = *(const uint4*)&Vt[(vtrow + r0s) * SEQ + cc0];
  uint4 va1 = *(const uint4*)&Vt[(vtrow + r1s) * SEQ + cc1];
  *(uint4*)&Ks[0][r0s * 72 + cc0] = ka0;
  *(uint4*)&Ks[0][r1s * 72 + cc1] = ka1;
  *(uint4*)&Vs[0][r0s * 72 + cc0] = va0;
  *(uint4*)&Vs[0][r1s * 72 + cc1] = va1;
  __syncthreads();

  #pragma unroll 2
  for (int ti = 0; ti < SEQ / 64; ++ti) {
    const int kb = ti * 64;
    const int cur = ti & 1;
    const u16* Kc = Ks[cur];
    const u16* Vc = Vs[cur];

    // issue next tile's global loads (land during this tile's compute)
    if (ti + 1 < SEQ / 64) {
      ka0 = *(const uint4*)&QKV[krow + (size_t)(kb + 64 + r0s) * QKVN + cc0];
      ka1 = *(const uint4*)&QKV[krow + (size_t)(kb + 64 + r1s) * QKVN + cc1];
      va0 = *(const uint4*)&Vt[(vtrow + r0s) * SEQ + kb + 64 + cc0];
      va1 = *(const uint4*)&Vt[(vtrow + r1s) * SEQ + kb + 64 + cc1];
    }

    // per-32-kpos half: QK(m) -> bias -> softmax -> bp (one f32x16 live)
    bf16x8 bp[4];
    #pragma unroll
    for (int m = 0; m < 2; ++m) {
      f32x16 sc;
      #pragma unroll
      for (int i = 0; i < 16; ++i) sc[i] = 0.f;
      __builtin_amdgcn_s_setprio(1);
      #pragma unroll
      for (int ks = 0; ks < 4; ++ks) {
        bf16x8 kf = *(const bf16x8*)&Kc[(m * 32 + l31) * 72 + ks * 16 + h5 * 8];
        sc = MFMA32(kf, qf[ks], sc);
      }
      __builtin_amdgcn_s_setprio(0);

      // fused pos_bias emission under QK(0)'s MFMA latency; tiles ti == b (mod 4)
      if (m == 0 && (ti & 3) == b) {
        const int pr = qb + (t >> 1);
        const int pc = kb + (t & 1) * 32;
        float* po = pb + ((size_t)(h * SEQ + pr)) * SEQ + pc;
        const int lo = pc - pr;
        if (lo >= 91 || lo + 31 <= -91) {
          const float c = (lo >= 91) ? cpu : cnu;
          const float4 vv = {c, c, c, c};
          #pragma unroll
          for (int i = 0; i < 8; ++i) *(float4*)&po[i * 4] = vv;
        } else {
          const float* bb = brel + h * 4096 + 2047 - pr + pc;
          #pragma unroll
          for (int i = 0; i < 8; ++i) {
            float4 vv;
            vv.x = bb[i * 4]; vv.y = bb[i * 4 + 1];
            vv.z = bb[i * 4 + 2]; vv.w = bb[i * 4 + 3];
            *(float4*)&po[i * 4] = vv;
          }
        }
      }

      const int kb32 = kb + 32 * m;
      if (kb32 >= qw0 + 122) {              // whole tile rel >= 91
        #pragma unroll
        for (int i = 0; i < 16; ++i) sc[i] += cpos;
      } else if (kb32 <= qw0 - 122) {       // whole tile rel <= -91
        #pragma unroll
        for (int i = 0; i < 16; ++i) sc[i] += cneg;
      } else {
        const float* bb = brow + kb32 + 4 * h5 - qr;   // + (reg&3) + 8*(reg>>2)
        #pragma unroll
        for (int i = 0; i < 16; ++i) sc[i] += bb[(i & 3) + 8 * (i >> 2)];
      }
      u32 w0[4], w1[4];
      #pragma unroll
      for (int tt = 0; tt < 4; ++tt) {
        float p0 = exp2fast(sc[4 * tt + 0]);
        float p1 = exp2fast(sc[4 * tt + 1]);
        float p2 = exp2fast(sc[4 * tt + 2]);
        float p3 = exp2fast(sc[4 * tt + 3]);
        lsum += (p0 + p1) + (p2 + p3);
        w0[tt] = pkbf_fast(p0, p1);
        w1[tt] = pkbf_fast(p2, p3);
      }
      // cross-half exchange: each lane assembles its PV B-frag directly
      u32x2 r0 = plswap(w0[0], w0[1]);
      u32x2 r1 = plswap(w1[0], w1[1]);
      u32x2 r2 = plswap(w0[2], w0[3]);
      u32x2 r3 = plswap(w1[2], w1[3]);
      union { u32 u[4]; bf16x8 v; } q0, q1;
      q0.u[0] = r0.x; q0.u[1] = r1.x; q0.u[2] = r0.y; q0.u[3] = r1.y;
      q1.u[0] = r2.x; q1.u[1] = r3.x; q1.u[2] = r2.y; q1.u[3] = r3.y;
      bp[2 * m]     = q0.v;
      bp[2 * m + 1] = q1.v;
    }

    // PV: A = V-frag from LDS, B = in-register P frags
    __builtin_amdgcn_s_setprio(1);
    #pragma unroll
    for (int m2 = 0; m2 < 2; ++m2)
      #pragma unroll
      for (int ks = 0; ks < 4; ++ks) {
        bf16x8 vf = *(const bf16x8*)&Vc[(m2 * 32 + l31) * 72 + ks * 16 + h5 * 8];
        oacc[m2] = MFMA32(vf, bp[ks], oacc[m2]);
      }
    __builtin_amdgcn_s_setprio(0);

    // publish next tile into the other buffer (loads have landed by now)
    if (ti + 1 < SEQ / 64) {
      u16* Kn = Ks[cur ^ 1];
      u16* Vn = Vs[cur ^ 1];
      *(uint4*)&Kn[r0s * 72 + cc0] = ka0;
      *(uint4*)&Kn[r1s * 72 + cc1] = ka1;
      *(uint4*)&Vn[r0s * 72 + cc0] = va0;
      *(uint4*)&Vn[r1s * 72 + cc1] = va1;
    }
    __syncthreads();
  }

  // epilogue: lane holds O^T[d][qr]: d = 32*m2 + 8*tt + 4*h5 + (reg&3)
  lsum += __shfl_xor(lsum, 32);
  const float inv = 1.0f / lsum;
  const size_t rowb = (size_t)(b * SEQ + qr) * DMODEL + h * 64;
  #pragma unroll
  for (int m2 = 0; m2 < 2; ++m2)
    #pragma unroll
    for (int tt = 0; tt < 4; ++tt) {
      uint2 o;
      o.x = pkbf(oacc[m2][4 * tt + 0] * inv, oacc[m2][4 * tt + 1] * inv);
      o.y = pkbf(oacc[m2][4 * tt + 2] * inv, oacc[m2][4 * tt + 3] * inv);
      *(uint2*)&Aout[rowb + 32 * m2 + 8 * tt + 4 * h5] = o;
    }
}

extern "C" void kernel_launch(void* const* d_in, const int* in_sizes, int n_in,
                              void* d_out, int out_size, void* d_ws, size_t ws_size,
                              hipStream_t stream) {
  (void)in_sizes; (void)n_in; (void)out_size; (void)ws_size;
  const float* H   = (const float*)d_in[0];
  const float* Wq  = (const float*)d_in[1];
  const float* Wk  = (const float*)d_in[2];
  const float* Wv  = (const float*)d_in[3];
  const float* Wo  = (const float*)d_in[4];
  const float* tbl = (const float*)d_in[5];

  float* out = (float*)d_out;                       // [8192][1024] fp32
  float* pos_bias = out + (size_t)MROWS * DMODEL;   // [16][2048][2048] fp32

  char* ws = (char*)d_ws;
  u16* Hb     = (u16*)(ws);                 // 16 MB  (reused as attn_out later)
  u16* Wt     = (u16*)(ws + 16777216);      // 8 MB   [4096][1024]
  u16* QKV    = (u16*)(ws + 25165824);      // 48 MB  [8192][3072]
  u16* Vt     = (u16*)(ws + 75497472);      // 16 MB  [4096][2048]
  float* brel  = (float*)(ws + 92274688);   // 256 KB [16][4096]  (unscaled)
  float* brel2 = (float*)(ws + 92536832);   // 256 KB [16][4096]  (x log2e)

  convert_h<<<8192, 256, 0, stream>>>(H, Hb);
  transpose_w<<<dim3(32, 32, 4), dim3(32, 8), 0, stream>>>(Wq, Wk, Wv, Wo, Wt);
  build_bias_rel<<<16, 256, 0, stream>>>(tbl, brel, brel2);

  // QKV = Hb @ [Wq|Wk|Wv]; V third written directly transposed into Vt
  gemm_bf16k<<<dim3(QKVN / 128, MROWS / 128), 256, 0, stream>>>(
      Hb, Wt, QKV, nullptr, Vt, MROWS, QKVN, DMODEL);
  attn_fused<<<dim3(16, 64), 256, 0, stream>>>(QKV, Vt, brel, brel2,
                                               Hb /* attn_out */, pos_bias);
  // out = attn_out @ Wo   (fp32 out)
  gemm_bf16k<<<dim3(DMODEL / 128, MROWS / 128), 256, 0, stream>>>(
      Hb, Wt + (size_t)QKVN * DMODEL, nullptr, out, nullptr, MROWS, DMODEL, DMODEL);
}